// Round 3
// baseline (234521.143 us; speedup 1.0000x reference)
//
#include <hip/hip_runtime.h>
#include <stdint.h>

#define U_ 1536
#define D_ 768
#define N_ 4096
#define UNF 6
#define LOG2E 1.4426950408889634f
#define NBLK 256
#define CPB 6            // columns per scan block
#define TPB 768          // threads per scan block
#define SG 8             // steps per sensory block
#define TOTAL_TAGS (N_*UNF)
#define NCTR 8           // partial counters (256B stride)

// ---------- helpers ----------
__device__ __forceinline__ uint32_t f2bf(float f) {
    uint32_t u = __float_as_uint(f);
    u += 0x7FFFu + ((u >> 16) & 1u);   // RNE to bf16
    return u >> 16;
}
__device__ __forceinline__ uint32_t pack2(float hi, float lo) {
    return (f2bf(hi) << 16) | f2bf(lo);
}

// ---------- K0: pack weights (bf16), rt, clear slots + counters ----------
__global__ void k_pack(const float* __restrict__ sigma, const float* __restrict__ mu,
                       const float* __restrict__ w, const float* __restrict__ erev,
                       const float* __restrict__ ssig, const float* __restrict__ smu,
                       const float* __restrict__ sw, const float* __restrict__ serev,
                       const float* __restrict__ dt,
                       uint2* __restrict__ pk_rec, uint2* __restrict__ pk_sens,
                       float* __restrict__ rt, float* __restrict__ vslot,
                       unsigned* __restrict__ ctr)
{
    int gsz = gridDim.x * blockDim.x;
    int g0  = blockIdx.x * blockDim.x + threadIdx.x;
    // recurrent pack, transposed to column-major [j][i]
    for (int o = g0; o < U_*U_; o += gsz) {
        int j = o / U_; int i = o - j*U_;
        int in = i*U_ + j;
        float sg = sigma[in] * LOG2E;
        float m  = mu[in];
        float wv = w[in];
        float ev = erev[in];
        uint2 p; p.x = pack2(sg, sg*m); p.y = pack2(wv, wv*ev);
        pk_rec[o] = p;
    }
    // sensory pack, same orientation [d][j]
    for (int o = g0; o < D_*U_; o += gsz) {
        float sg = ssig[o] * LOG2E;
        uint2 p; p.x = pack2(sg, sg*smu[o]); p.y = pack2(sw[o], sw[o]*serev[o]);
        pk_sens[o] = p;
    }
    for (int o = g0; o < N_; o += gsz) rt[o] = 6.0f / fmaxf(dt[o], 0.001f);
    for (int o = g0; o < 2*U_; o += gsz) vslot[o] = 0.0f;
    for (int o = g0; o < NCTR*64; o += gsz) ctr[o] = 0u;   // re-clear every launch (graph replay)
}

// ---------- K1: sensory sums for all steps ----------
__global__ __launch_bounds__(256) void k_sens(const float* __restrict__ x,
        const float* __restrict__ iw, const float* __restrict__ ib,
        const uint2* __restrict__ pk_sens, float2* __restrict__ sens)
{
    __shared__ float xs[SG][D_];
    int ct = blockIdx.x % 6;
    int g  = blockIdx.x / 6;
    int n0 = g * SG;
    for (int idx = threadIdx.x; idx < SG*D_; idx += 256) {
        int s = idx / D_, d = idx - s*D_;
        xs[s][d] = x[(size_t)(n0+s)*D_ + d] * iw[d] + ib[d];
    }
    __syncthreads();
    int j = ct*256 + threadIdx.x;
    float an[SG], bn[SG];
#pragma unroll
    for (int s = 0; s < SG; ++s) { an[s] = 0.0f; bn[s] = 0.0f; }
    for (int d = 0; d < D_; ++d) {
        uint2 m = pk_sens[d*U_ + j];
        float s2 = __uint_as_float(m.x & 0xFFFF0000u);
        float p2 = __uint_as_float(m.x << 16);
        float wv = __uint_as_float(m.y & 0xFFFF0000u);
        float wev= __uint_as_float(m.y << 16);
#pragma unroll
        for (int s = 0; s < SG; ++s) {
            float e  = __builtin_amdgcn_exp2f(fmaf(-s2, xs[s][d], p2));
            float sg = __builtin_amdgcn_rcpf(1.0f + e);
            an[s] = fmaf(wev, sg, an[s]);
            bn[s] = fmaf(wv,  sg, bn[s]);
        }
    }
#pragma unroll
    for (int s = 0; s < SG; ++s)
        sens[(size_t)(n0+s)*U_ + j] = make_float2(an[s], bn[s]);
}

// ---------- K2: persistent sequential scan ----------
__global__ __launch_bounds__(TPB, 1) void k_scan(
        const uint2* __restrict__ pk_rec, const float2* __restrict__ sens,
        const float* __restrict__ rt, float* __restrict__ vslot,
        unsigned* __restrict__ ctr,
        const float* __restrict__ gleak, const float* __restrict__ vleak,
        const float* __restrict__ cm, float* __restrict__ out)
{
    __shared__ float  v_s[U_];
    __shared__ uint2  pk_s[CPB*U_];
    __shared__ float2 part_s[CPB][2];
    __shared__ float2 sens_s[2][CPB];
    __shared__ float  rt_s[2];

    const int tid = threadIdx.x;
    const int b   = blockIdx.x;

    for (int o = tid; o < CPB*U_; o += TPB) pk_s[o] = pk_rec[(size_t)b*CPB*U_ + o];
    for (int o = tid; o < U_;     o += TPB) v_s[o] = 0.0f;

    // publisher lanes tid<6: per-column constants + running v in registers
    float glk = 0.0f, gvl = 0.0f, cmv = 0.0f, prev = 0.0f;
    if (tid < CPB) {
        int jg = b*CPB + tid;
        glk = gleak[jg]; gvl = glk * vleak[jg]; cmv = cm[jg];
    }
    if (tid >= 64 && tid < 64+CPB) sens_s[0][tid-64] = sens[(size_t)b*CPB + (tid-64)];
    if (tid == 70) rt_s[0] = rt[0];
    __syncthreads();

    const int col  = tid >> 7;    // 0..5 column group
    const int r0   = tid & 127;
    const int wv   = tid >> 6;    // wave 0..11
    const int lane = tid & 63;

    int tag = 1;
    for (int n = 0; n < N_; ++n) {
        float2 pf_sens = make_float2(0.0f, 0.0f);
        float  pf_rt = 0.0f;
        if (n + 1 < N_) {
            if (tid >= 64 && tid < 64+CPB) pf_sens = sens[(size_t)(n+1)*U_ + b*CPB + (tid-64)];
            if (tid == 70) pf_rt = rt[n+1];
        }
        for (int u = 0; u < UNF; ++u, ++tag) {
            float num0 = 0.0f, num1 = 0.0f, den0 = 0.0f, den1 = 0.0f;
            const uint2* colp = &pk_s[col*U_];
#pragma unroll
            for (int k = 0; k < 12; ++k) {
                int i = r0 + (k << 7);
                uint2 m  = colp[i];
                float vi = v_s[i];
                float s2 = __uint_as_float(m.x & 0xFFFF0000u);
                float p2 = __uint_as_float(m.x << 16);
                float wl = __uint_as_float(m.y & 0xFFFF0000u);
                float wel= __uint_as_float(m.y << 16);
                float e  = __builtin_amdgcn_exp2f(fmaf(-s2, vi, p2));
                float sg = __builtin_amdgcn_rcpf(1.0f + e);
                if (k & 1) { num1 = fmaf(wel, sg, num1); den1 = fmaf(wl, sg, den1); }
                else       { num0 = fmaf(wel, sg, num0); den0 = fmaf(wl, sg, den0); }
            }
            float num = num0 + num1, den = den0 + den1;
#pragma unroll
            for (int mk = 32; mk >= 1; mk >>= 1) {
                num += __shfl_xor(num, mk, 64);
                den += __shfl_xor(den, mk, 64);
            }
            if (lane == 0) part_s[wv >> 1][wv & 1] = make_float2(num, den);
            __syncthreads();                                   // B1

            const bool last = (tag == TOTAL_TAGS);
            if (tid < CPB) {
                float2 pa = part_s[tid][0], pb = part_s[tid][1];
                float rtv = rt_s[n & 1];
                float2 sv = sens_s[n & 1][tid];
                float cmt = cmv * rtv;
                float nm = cmt * prev + gvl + pa.x + pb.x + sv.x;
                float dn = cmt + glk + pa.y + pb.y + sv.y + 1e-8f;
                float vn = nm / dn;
                prev = vn;
                int jg = b*CPB + tid;
                if (last) out[jg] = vn;
                else __hip_atomic_store(&vslot[(size_t)(tag & 1)*U_ + jg], vn,
                                        __ATOMIC_RELAXED, __HIP_MEMORY_SCOPE_AGENT);
            }
            if (!last) {
                // publish completion: release-add so values are MALL-visible first
                if (tid == 0)
                    (void)__hip_atomic_fetch_add(&ctr[(b & (NCTR-1)) << 6], 1u,
                                                 __ATOMIC_RELEASE, __HIP_MEMORY_SCOPE_AGENT);
                // wave-1 lanes 0..7 poll the 8 counters (overlaps wave-0 publish fence)
                if (tid >= 64 && tid < 64 + NCTR) {
                    unsigned need = (unsigned)(NBLK/NCTR) * (unsigned)tag;
                    unsigned* cp = &ctr[(tid - 64) << 6];
                    int guard = 0;
                    while (__hip_atomic_load(cp, __ATOMIC_RELAXED, __HIP_MEMORY_SCOPE_AGENT) < need) {
                        if (++guard > (1 << 20)) break;        // visible fail, no hang
                        __builtin_amdgcn_s_sleep(1);
                    }
                }
                __syncthreads();                               // B2: all 256 publishes visible
                unsigned long long pkv = __hip_atomic_load(
                        (const unsigned long long*)&vslot[(size_t)(tag & 1)*U_] + tid,
                        __ATOMIC_RELAXED, __HIP_MEMORY_SCOPE_AGENT);
                v_s[2*tid]   = __uint_as_float((unsigned)pkv);
                v_s[2*tid+1] = __uint_as_float((unsigned)(pkv >> 32));
                if (u == UNF-1 && n + 1 < N_) {
                    if (tid >= 64 && tid < 64+CPB) sens_s[(n+1) & 1][tid-64] = pf_sens;
                    if (tid == 70) rt_s[(n+1) & 1] = pf_rt;
                }
                __syncthreads();                               // B3: v_s ready for next gates
            }
        }
    }
}

// ---------- launch ----------
extern "C" void kernel_launch(void* const* d_in, const int* in_sizes, int n_in,
                              void* d_out, int out_size, void* d_ws, size_t ws_size,
                              hipStream_t stream)
{
    (void)in_sizes; (void)n_in; (void)out_size;
    const float* x     = (const float*)d_in[0];
    const float* dt    = (const float*)d_in[1];
    const float* iw    = (const float*)d_in[2];
    const float* ib    = (const float*)d_in[3];
    const float* gleak = (const float*)d_in[4];
    const float* vleak = (const float*)d_in[5];
    const float* cm    = (const float*)d_in[6];
    const float* sigma = (const float*)d_in[7];
    const float* mu    = (const float*)d_in[8];
    const float* w     = (const float*)d_in[9];
    const float* erev  = (const float*)d_in[10];
    const float* ssig  = (const float*)d_in[11];
    const float* smu   = (const float*)d_in[12];
    const float* sw    = (const float*)d_in[13];
    const float* serev = (const float*)d_in[14];

    size_t need = (size_t)N_*U_*8 + (size_t)U_*U_*8 + (size_t)D_*U_*8 + (size_t)N_*4
                + (size_t)2*U_*4 + (size_t)NCTR*64*4;
    if (ws_size < need) return;   // insufficient scratch -> fail visibly

    char* ws = (char*)d_ws;
    float2*   sens   = (float2*)ws;               ws += (size_t)N_*U_*8;
    uint2*    pk_rec = (uint2*)ws;                ws += (size_t)U_*U_*8;
    uint2*    pk_sns = (uint2*)ws;                ws += (size_t)D_*U_*8;
    float*    rt     = (float*)ws;                ws += (size_t)N_*4;
    float*    vslot  = (float*)ws;                ws += (size_t)2*U_*4;
    unsigned* ctr    = (unsigned*)ws;

    k_pack<<<2048, 256, 0, stream>>>(sigma, mu, w, erev, ssig, smu, sw, serev, dt,
                                     pk_rec, pk_sns, rt, vslot, ctr);
    k_sens<<<(N_/SG)*6, 256, 0, stream>>>(x, iw, ib, pk_sns, sens);
    // 12 KiB dynamic LDS pad: static ~80 KB alone would allow 2 blocks/CU;
    // pad forces 1 block/CU so all 256 blocks are co-resident (spin-exchange safety).
    k_scan<<<NBLK, TPB, 12288, stream>>>(pk_rec, sens, rt, vslot, ctr,
                                         gleak, vleak, cm, (float*)d_out);
}

// Round 4
// 88750.250 us; speedup vs baseline: 2.6425x; 2.6425x over previous
//
#include <hip/hip_runtime.h>
#include <stdint.h>

#define U_ 1536
#define D_ 768
#define N_ 4096
#define UNF 6
#define LOG2E 1.4426950408889634f
#define NBLK 128
#define CPB 12           // columns per scan block
#define TPB 768          // threads per scan block
#define SG 8             // steps per sensory block
#define TOTAL_TAGS (N_*UNF)

typedef unsigned int uint4v __attribute__((ext_vector_type(4)));
typedef unsigned int uint2v __attribute__((ext_vector_type(2)));

// ---------- helpers ----------
__device__ __forceinline__ uint32_t f2bf(float f) {
    uint32_t u = __float_as_uint(f);
    u += 0x7FFFu + ((u >> 16) & 1u);   // RNE to bf16
    return u >> 16;
}
__device__ __forceinline__ uint32_t pack2(float hi, float lo) {
    return (f2bf(hi) << 16) | f2bf(lo);
}

// ---------- K0: pack weights (bf16), rt, clear board ----------
__global__ void k_pack(const float* __restrict__ sigma, const float* __restrict__ mu,
                       const float* __restrict__ w, const float* __restrict__ erev,
                       const float* __restrict__ ssig, const float* __restrict__ smu,
                       const float* __restrict__ sw, const float* __restrict__ serev,
                       const float* __restrict__ dt,
                       uint2* __restrict__ pk_rec, uint2* __restrict__ pk_sens,
                       float* __restrict__ rt, unsigned long long* __restrict__ vpub)
{
    int gsz = gridDim.x * blockDim.x;
    int g0  = blockIdx.x * blockDim.x + threadIdx.x;
    // recurrent pack, transposed to column-major [j][i]
    for (int o = g0; o < U_*U_; o += gsz) {
        int j = o / U_; int i = o - j*U_;
        int in = i*U_ + j;
        float sg = sigma[in] * LOG2E;
        float m  = mu[in];
        float wv = w[in];
        float ev = erev[in];
        uint2 p; p.x = pack2(sg, sg*m); p.y = pack2(wv, wv*ev);
        pk_rec[o] = p;
    }
    // sensory pack, same orientation [d][j]
    for (int o = g0; o < D_*U_; o += gsz) {
        float sg = ssig[o] * LOG2E;
        uint2 p; p.x = pack2(sg, sg*smu[o]); p.y = pack2(sw[o], sw[o]*serev[o]);
        pk_sens[o] = p;
    }
    for (int o = g0; o < N_; o += gsz) rt[o] = 6.0f / fmaxf(dt[o], 0.001f);
    for (int o = g0; o < 2*U_; o += gsz) vpub[o] = 0ull;   // clear board (graph replay)
}

// ---------- K1: sensory sums for all steps ----------
__global__ __launch_bounds__(256) void k_sens(const float* __restrict__ x,
        const float* __restrict__ iw, const float* __restrict__ ib,
        const uint2* __restrict__ pk_sens, float2* __restrict__ sens)
{
    __shared__ float xs[SG][D_];
    int ct = blockIdx.x % 6;
    int g  = blockIdx.x / 6;
    int n0 = g * SG;
    for (int idx = threadIdx.x; idx < SG*D_; idx += 256) {
        int s = idx / D_, d = idx - s*D_;
        xs[s][d] = x[(size_t)(n0+s)*D_ + d] * iw[d] + ib[d];
    }
    __syncthreads();
    int j = ct*256 + threadIdx.x;
    float an[SG], bn[SG];
#pragma unroll
    for (int s = 0; s < SG; ++s) { an[s] = 0.0f; bn[s] = 0.0f; }
    for (int d = 0; d < D_; ++d) {
        uint2 m = pk_sens[d*U_ + j];
        float s2 = __uint_as_float(m.x & 0xFFFF0000u);
        float p2 = __uint_as_float(m.x << 16);
        float wv = __uint_as_float(m.y & 0xFFFF0000u);
        float wev= __uint_as_float(m.y << 16);
#pragma unroll
        for (int s = 0; s < SG; ++s) {
            float e  = __builtin_amdgcn_exp2f(fmaf(-s2, xs[s][d], p2));
            float sg = __builtin_amdgcn_rcpf(1.0f + e);
            an[s] = fmaf(wev, sg, an[s]);
            bn[s] = fmaf(wv,  sg, bn[s]);
        }
    }
#pragma unroll
    for (int s = 0; s < SG; ++s)
        sens[(size_t)(n0+s)*U_ + j] = make_float2(an[s], bn[s]);
}

// ---------- K2: persistent sequential scan (128 blocks x 12 cols) ----------
__global__ __launch_bounds__(TPB, 1) void k_scan(
        const uint2* __restrict__ pk_rec, const float2* __restrict__ sens,
        const float* __restrict__ rt, unsigned long long* __restrict__ vpub,
        const float* __restrict__ gleak, const float* __restrict__ vleak,
        const float* __restrict__ cm, float* __restrict__ out)
{
    __shared__ float  v_s[U_];
    __shared__ uint2  pk_s[CPB*U_];      // 147456 B
    __shared__ float2 part_s[CPB];
    __shared__ float2 sens_s[2][CPB];
    __shared__ float  rt_s[2];

    const int tid = threadIdx.x;
    const int b   = blockIdx.x;

    for (int o = tid; o < CPB*U_; o += TPB) pk_s[o] = pk_rec[(size_t)b*CPB*U_ + o];
    for (int o = tid; o < U_;     o += TPB) v_s[o] = 0.0f;

    // publisher lanes tid<12: per-column constants + running v in registers
    float glk = 0.0f, gvl = 0.0f, cmv = 0.0f, prev = 0.0f;
    if (tid < CPB) {
        int jg = b*CPB + tid;
        glk = gleak[jg]; gvl = glk * vleak[jg]; cmv = cm[jg];
    }
    if (tid >= 64 && tid < 64+CPB) sens_s[0][tid-64] = sens[(size_t)b*CPB + (tid-64)];
    if (tid == 76) rt_s[0] = rt[0];
    __syncthreads();

    const int col  = tid >> 6;    // 0..11 column (one wave per column)
    const int lane = tid & 63;

    // poll mapping: 768 16B-chunks (2 columns each); own 6 chunks skipped
    const bool isPoll = (tid < 6*NBLK - 6);
    int c = 0;
    if (isPoll) c = tid + (tid >= 6*b ? 6 : 0);

    int tag = 1;
    for (int n = 0; n < N_; ++n) {
        float2 pf_sens = make_float2(0.0f, 0.0f);
        float  pf_rt = 0.0f;
        if (n + 1 < N_) {
            if (tid >= 64 && tid < 64+CPB) pf_sens = sens[(size_t)(n+1)*U_ + b*CPB + (tid-64)];
            if (tid == 76) pf_rt = rt[n+1];
        }
        for (int u = 0; u < UNF; ++u, ++tag) {
            float num0 = 0.0f, num1 = 0.0f, den0 = 0.0f, den1 = 0.0f;
            const uint2* colp = &pk_s[col*U_];
#pragma unroll
            for (int k = 0; k < 24; ++k) {
                int i = lane + (k << 6);
                uint2 m  = colp[i];
                float vi = v_s[i];
                float s2 = __uint_as_float(m.x & 0xFFFF0000u);
                float p2 = __uint_as_float(m.x << 16);
                float wl = __uint_as_float(m.y & 0xFFFF0000u);
                float wel= __uint_as_float(m.y << 16);
                float e  = __builtin_amdgcn_exp2f(fmaf(-s2, vi, p2));
                float sg = __builtin_amdgcn_rcpf(1.0f + e);
                if (k & 1) { num1 = fmaf(wel, sg, num1); den1 = fmaf(wl, sg, den1); }
                else       { num0 = fmaf(wel, sg, num0); den0 = fmaf(wl, sg, den0); }
            }
            float num = num0 + num1, den = den0 + den1;
#pragma unroll
            for (int mk = 32; mk >= 1; mk >>= 1) {
                num += __shfl_xor(num, mk, 64);
                den += __shfl_xor(den, mk, 64);
            }
            if (lane == 0) part_s[col] = make_float2(num, den);
            __syncthreads();                                   // B1

            const bool last = (tag == TOTAL_TAGS);
            if (tid < CPB) {
                float2 pd = part_s[tid];
                float rtv = rt_s[n & 1];
                float2 sv = sens_s[n & 1][tid];
                float cmt = cmv * rtv;
                float nm = cmt * prev + gvl + pd.x + sv.x;
                float dn = cmt + glk + pd.y + sv.y + 1e-8f;
                float vn = nm / dn;
                prev = vn;
                int jg = b*CPB + tid;
                v_s[jg] = vn;                                  // own values direct to LDS
                if (last) {
                    out[jg] = vn;
                } else {
                    // self-tagged 8B granule {val, tag}; 12 coalesced stores
                    uint2v pk; pk.x = __float_as_uint(vn); pk.y = (unsigned)tag;
                    uint64_t saddr = (uint64_t)vpub + (size_t)((tag & 1)*U_ + jg)*8;
                    asm volatile("global_store_dwordx2 %0, %1, off sc0 sc1"
                                 :: "v"(saddr), "v"(pk) : "memory");
                }
            }
            if (!last) {
                if (isPoll) {
                    unsigned t32 = (unsigned)tag;
                    uint64_t addr = (uint64_t)vpub + (size_t)(tag & 1)*U_*8 + (size_t)c*16;
                    uint4v pkt;
                    int guard = 0;
                    while (true) {
                        asm volatile("global_load_dwordx4 %0, %1, off sc0 sc1\n\t"
                                     "s_waitcnt vmcnt(0)"
                                     : "=v"(pkt) : "v"(addr) : "memory");
                        if (pkt.y == t32 && pkt.w == t32) break;
                        if (++guard > (1 << 21)) break;        // visible fail, no hang
                        if (guard > 4) __builtin_amdgcn_s_sleep(1);
                    }
                    float2 vv;
                    vv.x = __uint_as_float(pkt.x);
                    vv.y = __uint_as_float(pkt.z);
                    *(float2*)&v_s[2*c] = vv;                  // contiguous, conflict-free
                }
                if (u == UNF-1) {
                    if (tid >= 64 && tid < 64+CPB) sens_s[(n+1) & 1][tid-64] = pf_sens;
                    if (tid == 76) rt_s[(n+1) & 1] = pf_rt;
                }
                __syncthreads();                               // B2: v_s ready for next gates
            }
        }
    }
}

// ---------- launch ----------
extern "C" void kernel_launch(void* const* d_in, const int* in_sizes, int n_in,
                              void* d_out, int out_size, void* d_ws, size_t ws_size,
                              hipStream_t stream)
{
    (void)in_sizes; (void)n_in; (void)out_size;
    const float* x     = (const float*)d_in[0];
    const float* dt    = (const float*)d_in[1];
    const float* iw    = (const float*)d_in[2];
    const float* ib    = (const float*)d_in[3];
    const float* gleak = (const float*)d_in[4];
    const float* vleak = (const float*)d_in[5];
    const float* cm    = (const float*)d_in[6];
    const float* sigma = (const float*)d_in[7];
    const float* mu    = (const float*)d_in[8];
    const float* w     = (const float*)d_in[9];
    const float* erev  = (const float*)d_in[10];
    const float* ssig  = (const float*)d_in[11];
    const float* smu   = (const float*)d_in[12];
    const float* sw    = (const float*)d_in[13];
    const float* serev = (const float*)d_in[14];

    size_t need = (size_t)N_*U_*8 + (size_t)U_*U_*8 + (size_t)D_*U_*8 + (size_t)N_*4
                + (size_t)2*U_*8;
    if (ws_size < need) return;   // insufficient scratch -> fail visibly

    char* ws = (char*)d_ws;
    float2* sens   = (float2*)ws;                 ws += (size_t)N_*U_*8;
    uint2*  pk_rec = (uint2*)ws;                  ws += (size_t)U_*U_*8;
    uint2*  pk_sns = (uint2*)ws;                  ws += (size_t)D_*U_*8;
    float*  rt     = (float*)ws;                  ws += (size_t)N_*4;
    unsigned long long* vpub = (unsigned long long*)ws;

    k_pack<<<2048, 256, 0, stream>>>(sigma, mu, w, erev, ssig, smu, sw, serev, dt,
                                     pk_rec, pk_sns, rt, vpub);
    k_sens<<<(N_/SG)*6, 256, 0, stream>>>(x, iw, ib, pk_sns, sens);
    // 128 blocks x ~154 KiB static LDS -> exactly 1 block/CU, 128 < 256 CUs,
    // all blocks structurally co-resident (spin-exchange safe).
    k_scan<<<NBLK, TPB, 0, stream>>>(pk_rec, sens, rt, vpub,
                                     gleak, vleak, cm, (float*)d_out);
}